// Round 4
// baseline (66.930 us; speedup 1.0000x reference)
//
#include <hip/hip_runtime.h>
#include <hip/hip_bf16.h>

#define N_ROWS 8192
#define DIM 128
#define NUM_CLS 512
#define MARGIN_F 0.3f

typedef __attribute__((ext_vector_type(8))) short short8;
typedef __attribute__((ext_vector_type(4))) float f32x4;
typedef __attribute__((ext_vector_type(4))) int int4v;

// ---------------- Kernel S1: class histogram + exclusive prefix ------------
__global__ __launch_bounds__(512) void hist_kernel(
    const int* __restrict__ tgt, int* __restrict__ class_start) {
  __shared__ int h[NUM_CLS];
  const int t = threadIdx.x;
  h[t] = 0;
  __syncthreads();
  for (int i = t; i < N_ROWS; i += 512) atomicAdd(&h[tgt[i]], 1);
  __syncthreads();
  int own = h[t];
  int incl = own;
  #pragma unroll
  for (int off = 1; off < NUM_CLS; off <<= 1) {
    int v = (t >= off) ? h[t - off] : 0;
    __syncthreads();
    incl += v;
    h[t] = incl;
    __syncthreads();
  }
  class_start[t] = incl - own;   // exclusive prefix
}

// ---------------- Kernel S2: stable scatter (one wave per class) -----------
// Deterministic: within-class order preserved via ballot+popcount ranks.
__global__ __launch_bounds__(256) void scatter_kernel(
    const int* __restrict__ tgt, const int* __restrict__ class_start,
    int* __restrict__ sorted_row, int* __restrict__ cls) {
  const int c = blockIdx.x * 4 + (threadIdx.x >> 6);  // class id, 0..511
  const int l = threadIdx.x & 63;
  const int base = class_start[c];
  int cnt = 0;
  for (int i0 = 0; i0 < N_ROWS; i0 += 64) {
    int ti = tgt[i0 + l];
    unsigned long long m = __ballot(ti == c);
    if (ti == c) {
      int rank = __popcll(m & ((1ull << l) - 1ull));
      int pos = base + cnt + rank;
      sorted_row[pos] = i0 + l;
      cls[pos] = c;
    }
    cnt += __popcll(m);
  }
}

// ---------------- Kernel A: fp32 -> bf16 (fragment-major, sorted), norms ---
// Fragment-major: 16B unit u = c16*256 + kk*64 + l4*16 + l15 holds bf16 elems
// [kk*32 + l4*8 .. +8) of sorted row (c16*16 + l15). MFMA fragment load for
// 16-row panel c16 is xf[c16*256 + kk*64 + lane] -- 64 lanes contiguous.
__global__ __launch_bounds__(256) void prep_kernel(
    const float* __restrict__ x, const int* __restrict__ sorted_row,
    unsigned short* __restrict__ xbB, float* __restrict__ sqv,
    int* __restrict__ apb, int* __restrict__ anb) {
  const int w = threadIdx.x >> 6, l = threadIdx.x & 63;
  const int j = blockIdx.x * 4 + w;          // sorted position
  const int row = sorted_row[j];
  float2 v = reinterpret_cast<const float2*>(x + (size_t)row * DIM)[l];
  __hip_bfloat16 b0 = __float2bfloat16(v.x);
  __hip_bfloat16 b1 = __float2bfloat16(v.y);
  ushort2 st;
  st.x = *reinterpret_cast<unsigned short*>(&b0);
  st.y = *reinterpret_cast<unsigned short*>(&b1);
  const int c16 = j >> 4, l15r = j & 15;
  const int unit = c16 * 256 + (l >> 4) * 64 + ((l >> 2) & 3) * 16 + l15r;
  reinterpret_cast<ushort2*>(xbB)[unit * 4 + (l & 3)] = st;

  float s = v.x * v.x + v.y * v.y;
  #pragma unroll
  for (int off = 32; off >= 1; off >>= 1) s += __shfl_xor(s, off);
  if (l == 0) {
    sqv[j] = s;
    apb[j] = 0x00000000;            // 0.0f (max identity; diagonal is positive)
    anb[j] = 0x7f800000;            // +inf (min identity)
  }
}

// ---------------- Kernel B: fused Gram (bf16 MFMA) + batch-hard mining -----
// NO LDS, NO barriers. grid (64 row-blocks, 16 col-chunks); 4 waves/block.
// Wave = 32 rows x 64 cols per tile, 8 tiles. Rows sorted by class ->
// a col-tile is wave-uniformly all-negative unless class ranges overlap
// (~3% of tiles): clean path = fma + min3 chains only, no class compare.
__global__ __launch_bounds__(256, 4) void gram_mine_kernel(
    const unsigned short* __restrict__ xbB, const float* __restrict__ sqv,
    const int* __restrict__ cls, int* __restrict__ apb, int* __restrict__ anb) {
  const int t = threadIdx.x;
  const int w = t >> 6, l = t & 63;
  const int l15 = l & 15, l4 = l >> 4;
  const int rb = blockIdx.x * 128 + w * 32;      // wave's row base (sorted space)
  const int chunkbase = blockIdx.y * 512;        // 512 cols per chunk (8 tiles)

  const short8* xf = reinterpret_cast<const short8*>(xbB);  // 16B units

  // A fragments: panel c16 = rb/16 + rf
  short8 a[2][4];
  #pragma unroll
  for (int rf = 0; rf < 2; ++rf)
    #pragma unroll
    for (int kk = 0; kk < 4; ++kk)
      a[rf][kk] = xf[(rb >> 4 << 8) + rf * 256 + kk * 64 + l];

  // wave's class range (sorted => monotone)
  const int rcl_lo = cls[rb], rcl_hi = cls[rb + 31];

  // per-lane row classes for masked tiles (C/D rows: rb + rf*16 + l4*4 + rg)
  int t_r[8];
  #pragma unroll
  for (int rf = 0; rf < 2; ++rf)
    #pragma unroll
    for (int rg = 0; rg < 4; ++rg)
      t_r[rf * 4 + rg] = cls[rb + rf * 16 + l4 * 4 + rg];

  // mining state on v = sqc - 2*s (row term +sq_r deferred to the end)
  float ap2[8], an2[8];
  #pragma unroll
  for (int i = 0; i < 8; ++i) { ap2[i] = -__builtin_inff(); an2[i] = __builtin_inff(); }

  for (int ct = 0; ct < 8; ++ct) {
    const int colbase = chunkbase + ct * 64;
    const int cb16 = colbase >> 4;

    // column metadata (issue early; in flight during MFMAs)
    float sqc[4];
    #pragma unroll
    for (int cf = 0; cf < 4; ++cf) sqc[cf] = sqv[colbase + cf * 16 + l15];
    const int ccl_lo = cls[colbase], ccl_hi = cls[colbase + 63];
    const bool clean = (ccl_hi < rcl_lo) || (ccl_lo > rcl_hi);

    f32x4 acc[2][4];
    #pragma unroll
    for (int rf = 0; rf < 2; ++rf)
      #pragma unroll
      for (int cf = 0; cf < 4; ++cf) acc[rf][cf] = (f32x4){0.f, 0.f, 0.f, 0.f};

    #pragma unroll
    for (int kk = 0; kk < 4; ++kk) {
      #pragma unroll
      for (int cf = 0; cf < 4; ++cf) {
        short8 b = xf[(cb16 + cf) * 256 + kk * 64 + l];
        acc[0][cf] = __builtin_amdgcn_mfma_f32_16x16x32_bf16(a[0][kk], b, acc[0][cf], 0, 0, 0);
        acc[1][cf] = __builtin_amdgcn_mfma_f32_16x16x32_bf16(a[1][kk], b, acc[1][cf], 0, 0, 0);
      }
    }

    if (clean) {
      // all-negative tile: no class test, min3-fused reduction
      #pragma unroll
      for (int rf = 0; rf < 2; ++rf)
        #pragma unroll
        for (int rg = 0; rg < 4; ++rg) {
          int idx = rf * 4 + rg;
          float v0 = fmaf(-2.f, acc[rf][0][rg], sqc[0]);
          float v1 = fmaf(-2.f, acc[rf][1][rg], sqc[1]);
          float v2 = fmaf(-2.f, acc[rf][2][rg], sqc[2]);
          float v3 = fmaf(-2.f, acc[rf][3][rg], sqc[3]);
          an2[idx] = fminf(fminf(fminf(v0, v1), fminf(v2, v3)), an2[idx]);
        }
    } else {
      // mixed tile (~3%): full class-compare path, updates ap and an
      int tc[4];
      #pragma unroll
      for (int cf = 0; cf < 4; ++cf) tc[cf] = cls[colbase + cf * 16 + l15];
      #pragma unroll
      for (int cf = 0; cf < 4; ++cf) {
        #pragma unroll
        for (int rf = 0; rf < 2; ++rf)
          #pragma unroll
          for (int rg = 0; rg < 4; ++rg) {
            int idx = rf * 4 + rg;
            float v = fmaf(-2.f, acc[rf][cf][rg], sqc[cf]);
            bool pos = (t_r[idx] == tc[cf]);
            ap2[idx] = pos ? fmaxf(ap2[idx], v) : ap2[idx];
            an2[idx] = pos ? an2[idx] : fminf(an2[idx], v);
          }
      }
    }
  }

  // reduce across the 16 lanes (same l4 group = same rows, different cols)
  #pragma unroll
  for (int i = 0; i < 8; ++i) {
    #pragma unroll
    for (int off = 1; off < 16; off <<= 1) {
      ap2[i] = fmaxf(ap2[i], __shfl_xor(ap2[i], off));
      an2[i] = fminf(an2[i], __shfl_xor(an2[i], off));
    }
  }
  if (l15 == 0) {
    #pragma unroll
    for (int rf = 0; rf < 2; ++rf)
      #pragma unroll
      for (int rg = 0; rg < 4; ++rg) {
        int row = rb + rf * 16 + l4 * 4 + rg;
        float sqr = sqv[row];
        // d^2 = v + sq_r; clamp >=1e-12 commutes with max/min; non-negative
        // floats are int-monotone -> int atomics give exact fp max/min.
        float a2 = fmaxf(ap2[rf * 4 + rg] + sqr, 1e-12f);
        float n2 = fmaxf(an2[rf * 4 + rg] + sqr, 1e-12f);
        atomicMax(apb + row, __float_as_int(a2));
        atomicMin(anb + row, __float_as_int(n2));
      }
  }
}

// ---------------- Kernel C: loss = mean(relu(sqrt(ap2)-sqrt(an2)+margin)) --
__global__ __launch_bounds__(1024) void loss_kernel(
    const int4v* __restrict__ apb, const int4v* __restrict__ anb,
    float* __restrict__ out) {
  __shared__ float red[16];
  float s = 0.f;
  for (int i = threadIdx.x; i < N_ROWS / 4; i += 1024) {
    int4v a4 = apb[i], n4 = anb[i];
    #pragma unroll
    for (int j = 0; j < 4; ++j) {
      float ap = sqrtf(__int_as_float(a4[j]));
      float an = sqrtf(__int_as_float(n4[j]));   // +inf sentinel -> relu(-inf)=0
      float li = ap - an + MARGIN_F;
      s += li > 0.f ? li : 0.f;
    }
  }
  #pragma unroll
  for (int off = 32; off >= 1; off >>= 1) s += __shfl_xor(s, off);
  const int w = threadIdx.x >> 6, l = threadIdx.x & 63;
  if (l == 0) red[w] = s;
  __syncthreads();
  if (threadIdx.x < 16) {
    float v = red[threadIdx.x];
    #pragma unroll
    for (int off = 8; off >= 1; off >>= 1) v += __shfl_xor(v, off);
    if (threadIdx.x == 0) out[0] = v / (float)N_ROWS;
  }
}

extern "C" void kernel_launch(void* const* d_in, const int* in_sizes, int n_in,
                              void* d_out, int out_size, void* d_ws, size_t ws_size,
                              hipStream_t stream) {
  const float* x = (const float*)d_in[0];
  const int* tgt = (const int*)d_in[1];
  float* out = (float*)d_out;

  char* ws = (char*)d_ws;
  unsigned short* xbB = (unsigned short*)ws;                 // 2 MB fragment-major bf16
  float* sqv = (float*)(ws + 2097152);                       // 32 KB row norms
  int* cls = (int*)(ws + 2097152 + 32768);                   // 32 KB sorted classes
  int* apb = (int*)(ws + 2097152 + 65536);                   // 32 KB ap^2 bits
  int* anb = (int*)(ws + 2097152 + 98304);                   // 32 KB an^2 bits
  int* sorted_row = (int*)(ws + 2097152 + 131072);           // 32 KB perm
  int* class_start = (int*)(ws + 2097152 + 163840);          // 2 KB bins

  hist_kernel<<<1, 512, 0, stream>>>(tgt, class_start);
  scatter_kernel<<<128, 256, 0, stream>>>(tgt, class_start, sorted_row, cls);
  prep_kernel<<<2048, 256, 0, stream>>>(x, sorted_row, xbB, sqv, apb, anb);
  gram_mine_kernel<<<dim3(64, 16), 256, 0, stream>>>(xbB, sqv, cls, apb, anb);
  loss_kernel<<<1, 1024, 0, stream>>>((const int4v*)apb, (const int4v*)anb, out);
}

// Round 5
// 49.595 us; speedup vs baseline: 1.3495x; 1.3495x over previous
//
#include <hip/hip_runtime.h>
#include <hip/hip_bf16.h>

#define N_ROWS 8192
#define DIM 128
#define MARGIN_F 0.3f

typedef __attribute__((ext_vector_type(8))) short short8;
typedef __attribute__((ext_vector_type(4))) float f32x4;
typedef __attribute__((ext_vector_type(4))) int int4v;

// ---------------- Kernel A: fp32 -> bf16 (fragment-major), norms, init ----
// Fragment-major layout: 16B unit u = c16*256 + kk*64 + l4*16 + l15 holds
// bf16 elems [kk*32 + l4*8 .. +8) of row (c16*16 + l15). An MFMA A/B-fragment
// load for 16-row panel c16 is xf[c16*256 + kk*64 + lane]: 64 lanes contiguous.
__global__ __launch_bounds__(256) void prep_kernel(
    const float* __restrict__ x, const int* __restrict__ tgt,
    unsigned short* __restrict__ xbB, float2* __restrict__ meta,
    int* __restrict__ apb, int* __restrict__ anb) {
  const int w = threadIdx.x >> 6, l = threadIdx.x & 63;
  const int row = blockIdx.x * 4 + w;
  float2 v = reinterpret_cast<const float2*>(x + (size_t)row * DIM)[l];
  __hip_bfloat16 b0 = __float2bfloat16(v.x);
  __hip_bfloat16 b1 = __float2bfloat16(v.y);
  ushort2 st;
  st.x = *reinterpret_cast<unsigned short*>(&b0);
  st.y = *reinterpret_cast<unsigned short*>(&b1);
  // lane l holds elems 2l,2l+1 = chunk (kk=l>>4, l4=(l>>2)&3), byte (l&3)*4
  const int c16 = row >> 4, l15r = row & 15;
  const int unit = c16 * 256 + (l >> 4) * 64 + ((l >> 2) & 3) * 16 + l15r;
  reinterpret_cast<ushort2*>(xbB)[unit * 4 + (l & 3)] = st;

  float s = v.x * v.x + v.y * v.y;
  #pragma unroll
  for (int off = 32; off >= 1; off >>= 1) s += __shfl_xor(s, off);
  if (l == 0) {
    float2 m;
    m.x = s;
    m.y = __int_as_float(tgt[row]);   // raw bit carry; only ever bit-compared
    meta[row] = m;
    apb[row] = 0x00000000;            // 0.0f (max identity; diagonal is positive)
    anb[row] = 0x7f800000;            // +inf (min identity)
  }
}

// ---------------- Kernel B: fused Gram (bf16 MFMA) + batch-hard mining -----
// NO LDS, NO barriers. grid (32 row-blocks, 16 col-chunks) = 512 blocks
// (2/CU, 8 waves/CU at ~230 VGPR). Wave = 64 rows x 64 cols per tile,
// 8 tiles. A frags (64 rows x K=128) pinned in registers; B frags streamed
// from L1/L2 with a kk-level register double-buffer so loads for kk+1 are
// in flight under the 16 MFMAs of kk (covers ~200cy L2 latency in-wave).
__global__ __launch_bounds__(256, 2) void gram_mine_kernel(
    const unsigned short* __restrict__ xbB, const float2* __restrict__ meta,
    int* __restrict__ apb, int* __restrict__ anb) {
  const int t = threadIdx.x;
  const int w = t >> 6, l = t & 63;
  const int l15 = l & 15, l4 = l >> 4;
  const int rb = blockIdx.x * 256 + w * 64;      // wave's global row base
  const int chunkbase = blockIdx.y * 512;        // 512 cols per chunk (8 tiles)

  const short8* xf = reinterpret_cast<const short8*>(xbB);  // 16B units

  // A fragments: panels (rb>>4)+rf, rf=0..3 (rows rb..rb+63)
  short8 a[4][4];
  #pragma unroll
  for (int rf = 0; rf < 4; ++rf)
    #pragma unroll
    for (int kk = 0; kk < 4; ++kk)
      a[rf][kk] = xf[((rb >> 4) + rf) * 256 + kk * 64 + l];

  // per-lane row classes (C/D layout rows: rb + rf*16 + l4*4 + rg)
  int t_r[16];
  #pragma unroll
  for (int rf = 0; rf < 4; ++rf)
    #pragma unroll
    for (int rg = 0; rg < 4; ++rg)
      t_r[rf * 4 + rg] = __float_as_int(meta[rb + rf * 16 + l4 * 4 + rg].y);

  // mining state on v = sqc - 2*s (row term +sq_r deferred to the end)
  float ap2[16], an2[16];
  #pragma unroll
  for (int i = 0; i < 16; ++i) { ap2[i] = -__builtin_inff(); an2[i] = __builtin_inff(); }

  // B register double-buffer; prologue: tile 0, kk 0
  short8 bb[2][4];
  #pragma unroll
  for (int cf = 0; cf < 4; ++cf)
    bb[0][cf] = xf[((chunkbase >> 4) + cf) * 256 + l];

  for (int ct = 0; ct < 8; ++ct) {
    const int colbase = chunkbase + ct * 64;
    const int cb16 = colbase >> 4;
    // next tile's base for the cross-tile prefetch (clamped: last is dead load)
    const int nb16 = (chunkbase + ((ct < 7) ? (ct + 1) : ct) * 64) >> 4;

    // column metadata: issued early, consumed only in the epilogue
    float sqc[4]; int tc[4];
    #pragma unroll
    for (int cf = 0; cf < 4; ++cf) {
      float2 m = meta[colbase + cf * 16 + l15];
      sqc[cf] = m.x; tc[cf] = __float_as_int(m.y);
    }

    f32x4 acc[4][4];
    #pragma unroll
    for (int rf = 0; rf < 4; ++rf)
      #pragma unroll
      for (int cf = 0; cf < 4; ++cf) acc[rf][cf] = (f32x4){0.f, 0.f, 0.f, 0.f};

    #pragma unroll
    for (int kk = 0; kk < 4; ++kk) {
      // prefetch kk+1 (same tile) or kk=0 of next tile into the other buffer
      if (kk < 3) {
        #pragma unroll
        for (int cf = 0; cf < 4; ++cf)
          bb[(kk + 1) & 1][cf] = xf[(cb16 + cf) * 256 + (kk + 1) * 64 + l];
      } else {
        #pragma unroll
        for (int cf = 0; cf < 4; ++cf)
          bb[0][cf] = xf[(nb16 + cf) * 256 + l];
      }
      #pragma unroll
      for (int cf = 0; cf < 4; ++cf)
        #pragma unroll
        for (int rf = 0; rf < 4; ++rf)
          acc[rf][cf] = __builtin_amdgcn_mfma_f32_16x16x32_bf16(
              a[rf][kk], bb[kk & 1][cf], acc[rf][cf], 0, 0, 0);
    }

    // mining epilogue on v = sqc - 2s (monotone in d^2 per row)
    #pragma unroll
    for (int cf = 0; cf < 4; ++cf) {
      #pragma unroll
      for (int rf = 0; rf < 4; ++rf)
        #pragma unroll
        for (int rg = 0; rg < 4; ++rg) {
          int idx = rf * 4 + rg;
          float v = fmaf(-2.f, acc[rf][cf][rg], sqc[cf]);
          bool pos = (t_r[idx] == tc[cf]);
          ap2[idx] = pos ? fmaxf(ap2[idx], v) : ap2[idx];
          an2[idx] = pos ? an2[idx] : fminf(an2[idx], v);
        }
    }
  }

  // reduce across the 16 lanes (same l4 group = same rows, different cols)
  #pragma unroll
  for (int i = 0; i < 16; ++i) {
    #pragma unroll
    for (int off = 1; off < 16; off <<= 1) {
      ap2[i] = fmaxf(ap2[i], __shfl_xor(ap2[i], off));
      an2[i] = fminf(an2[i], __shfl_xor(an2[i], off));
    }
  }
  if (l15 == 0) {
    #pragma unroll
    for (int rf = 0; rf < 4; ++rf)
      #pragma unroll
      for (int rg = 0; rg < 4; ++rg) {
        int row = rb + rf * 16 + l4 * 4 + rg;
        float sqr = meta[row].x;
        // d^2 = v + sq_r; clamp >=1e-12 commutes with max/min; non-negative
        // floats are int-monotone -> int atomics give exact fp max/min.
        float a2 = fmaxf(ap2[rf * 4 + rg] + sqr, 1e-12f);
        float n2 = fmaxf(an2[rf * 4 + rg] + sqr, 1e-12f);
        atomicMax(apb + row, __float_as_int(a2));
        atomicMin(anb + row, __float_as_int(n2));
      }
  }
}

// ---------------- Kernel C: loss = mean(relu(sqrt(ap2)-sqrt(an2)+margin)) --
__global__ __launch_bounds__(1024) void loss_kernel(
    const int4v* __restrict__ apb, const int4v* __restrict__ anb,
    float* __restrict__ out) {
  __shared__ float red[16];
  float s = 0.f;
  for (int i = threadIdx.x; i < N_ROWS / 4; i += 1024) {
    int4v a4 = apb[i], n4 = anb[i];
    #pragma unroll
    for (int j = 0; j < 4; ++j) {
      float ap = sqrtf(__int_as_float(a4[j]));
      float an = sqrtf(__int_as_float(n4[j]));   // +inf sentinel -> relu(-inf)=0
      float li = ap - an + MARGIN_F;
      s += li > 0.f ? li : 0.f;
    }
  }
  #pragma unroll
  for (int off = 32; off >= 1; off >>= 1) s += __shfl_xor(s, off);
  const int w = threadIdx.x >> 6, l = threadIdx.x & 63;
  if (l == 0) red[w] = s;
  __syncthreads();
  if (threadIdx.x < 16) {
    float v = red[threadIdx.x];
    #pragma unroll
    for (int off = 8; off >= 1; off >>= 1) v += __shfl_xor(v, off);
    if (threadIdx.x == 0) out[0] = v / (float)N_ROWS;
  }
}

extern "C" void kernel_launch(void* const* d_in, const int* in_sizes, int n_in,
                              void* d_out, int out_size, void* d_ws, size_t ws_size,
                              hipStream_t stream) {
  const float* x = (const float*)d_in[0];
  const int* tgt = (const int*)d_in[1];
  float* out = (float*)d_out;

  char* ws = (char*)d_ws;
  unsigned short* xbB = (unsigned short*)ws;                // 2 MB fragment-major bf16
  float2* meta = (float2*)(ws + 2097152);                   // 64 KB (sq, tgt)
  int* apb = (int*)(ws + 2097152 + 65536);                  // 32 KB ap^2 bits
  int* anb = (int*)(ws + 2097152 + 65536 + 32768);          // 32 KB an^2 bits

  prep_kernel<<<2048, 256, 0, stream>>>(x, tgt, xbB, meta, apb, anb);
  gram_mine_kernel<<<dim3(32, 16), 256, 0, stream>>>(xbB, meta, apb, anb);
  loss_kernel<<<1, 1024, 0, stream>>>((const int4v*)apb, (const int4v*)anb, out);
}

// Round 6
// 48.665 us; speedup vs baseline: 1.3753x; 1.0191x over previous
//
#include <hip/hip_runtime.h>
#include <hip/hip_bf16.h>

#define N_ROWS 8192
#define DIM 128
#define MARGIN_F 0.3f

typedef __attribute__((ext_vector_type(8))) short short8;
typedef __attribute__((ext_vector_type(4))) float f32x4;
typedef __attribute__((ext_vector_type(4))) int int4v;

// ---------------- Kernel A: fp32 -> bf16 (fragment-major), norms, init ----
// Fragment-major layout: 16B unit u = c16*256 + kk*64 + l4*16 + l15 holds
// bf16 elems [kk*32 + l4*8 .. +8) of row (c16*16 + l15). An MFMA A/B-fragment
// load for 16-row panel c16 is xf[c16*256 + kk*64 + lane]: 64 lanes contiguous.
__global__ __launch_bounds__(256) void prep_kernel(
    const float* __restrict__ x, const int* __restrict__ tgt,
    unsigned short* __restrict__ xbB, float2* __restrict__ meta,
    int* __restrict__ apb, int* __restrict__ anb) {
  const int w = threadIdx.x >> 6, l = threadIdx.x & 63;
  const int row = blockIdx.x * 4 + w;
  float2 v = reinterpret_cast<const float2*>(x + (size_t)row * DIM)[l];
  __hip_bfloat16 b0 = __float2bfloat16(v.x);
  __hip_bfloat16 b1 = __float2bfloat16(v.y);
  ushort2 st;
  st.x = *reinterpret_cast<unsigned short*>(&b0);
  st.y = *reinterpret_cast<unsigned short*>(&b1);
  // lane l holds elems 2l,2l+1 = chunk (kk=l>>4, l4=(l>>2)&3), byte (l&3)*4
  const int c16 = row >> 4, l15r = row & 15;
  const int unit = c16 * 256 + (l >> 4) * 64 + ((l >> 2) & 3) * 16 + l15r;
  reinterpret_cast<ushort2*>(xbB)[unit * 4 + (l & 3)] = st;

  float s = v.x * v.x + v.y * v.y;
  #pragma unroll
  for (int off = 32; off >= 1; off >>= 1) s += __shfl_xor(s, off);
  if (l == 0) {
    float2 m;
    m.x = s;
    m.y = __int_as_float(tgt[row]);   // raw bit carry; only ever bit-compared
    meta[row] = m;
    apb[row] = 0x00000000;            // 0.0f (max identity; diagonal is positive)
    anb[row] = 0x7f800000;            // +inf (min identity)
  }
}

// ---------------- Kernel B: fused Gram (bf16 MFMA) + batch-hard mining -----
// NO LDS, NO barriers. grid (64 row-blocks, 32 col-chunks) = 2048 blocks,
// 8192 waves = 8/SIMD queued; ~155 combined regs -> 3 waves/SIMD resident.
// Wave = 32 rows x 64 cols per tile, 4 tiles (256-col chunk). 4 waves of a
// block share the same B cols (L1 reuse). B is kk-ping-pong double-buffered;
// the cross-tile prefetch (next tile's kk=0 B + meta) issues BEFORE the long
// epilogue, so tile-start L2 latency is covered in-wave.
__global__ __launch_bounds__(256, 3) void gram_mine_kernel(
    const unsigned short* __restrict__ xbB, const float2* __restrict__ meta,
    int* __restrict__ apb, int* __restrict__ anb) {
  const int t = threadIdx.x;
  const int w = t >> 6, l = t & 63;
  const int l15 = l & 15, l4 = l >> 4;
  const int rb = blockIdx.x * 128 + w * 32;      // wave's global row base
  const int chunk = blockIdx.y * 256;            // 256 cols per chunk (4 tiles)

  const short8* xf = reinterpret_cast<const short8*>(xbB);  // 16B units

  // A fragments: panels (rb>>4), (rb>>4)+1 (rows rb..rb+31)
  short8 a0[4], a1[4];
  #pragma unroll
  for (int kk = 0; kk < 4; ++kk) {
    a0[kk] = xf[(rb >> 4) * 256 + kk * 64 + l];
    a1[kk] = xf[((rb >> 4) + 1) * 256 + kk * 64 + l];
  }

  // per-lane row classes (C/D layout rows: rb + rf*16 + l4*4 + rg)
  int t_r[8];
  #pragma unroll
  for (int rf = 0; rf < 2; ++rf)
    #pragma unroll
    for (int rg = 0; rg < 4; ++rg)
      t_r[rf * 4 + rg] = __float_as_int(meta[rb + rf * 16 + l4 * 4 + rg].y);

  // mining state on v = sqc - 2*s (row term +sq_r deferred to the end)
  float ap2[8], an2[8];
  #pragma unroll
  for (int i = 0; i < 8; ++i) { ap2[i] = -__builtin_inff(); an2[i] = __builtin_inff(); }

  // B ping-pong buffer over kk: bb[kk&1][cf]
  short8 bb[2][4];
  float2 mc[4];                      // current tile's (sq, class) per cf
  const int cb0 = chunk >> 4;
  #pragma unroll
  for (int cf = 0; cf < 4; ++cf) {
    bb[0][cf] = xf[(cb0 + cf) * 256 + l];            // tile0, kk=0
    mc[cf] = meta[chunk + cf * 16 + l15];
  }

  #pragma unroll
  for (int ct = 0; ct < 4; ++ct) {
    const int cb16 = (chunk >> 4) + ct * 4;
    // next tile base (last tile: dead re-load of itself; stays in-bounds)
    const int nt = (ct < 3) ? (ct + 1) : 3;
    const int nb16 = (chunk >> 4) + nt * 4;

    f32x4 acc[2][4];
    #pragma unroll
    for (int rf = 0; rf < 2; ++rf)
      #pragma unroll
      for (int cf = 0; cf < 4; ++cf) acc[rf][cf] = (f32x4){0.f, 0.f, 0.f, 0.f};

    float2 mn[4];
    #pragma unroll
    for (int kk = 0; kk < 4; ++kk) {
      // prefetch into the other parity: kk+1 of this tile, or kk=0 of next
      if (kk < 3) {
        #pragma unroll
        for (int cf = 0; cf < 4; ++cf)
          bb[(kk + 1) & 1][cf] = xf[(cb16 + cf) * 256 + (kk + 1) * 64 + l];
      } else {
        #pragma unroll
        for (int cf = 0; cf < 4; ++cf)
          bb[0][cf] = xf[(nb16 + cf) * 256 + l];
        #pragma unroll
        for (int cf = 0; cf < 4; ++cf)
          mn[cf] = meta[chunk + nt * 64 + cf * 16 + l15];
      }
      #pragma unroll
      for (int cf = 0; cf < 4; ++cf) {
        acc[0][cf] = __builtin_amdgcn_mfma_f32_16x16x32_bf16(
            a0[kk], bb[kk & 1][cf], acc[0][cf], 0, 0, 0);
        acc[1][cf] = __builtin_amdgcn_mfma_f32_16x16x32_bf16(
            a1[kk], bb[kk & 1][cf], acc[1][cf], 0, 0, 0);
      }
    }

    // mining epilogue on v = sqc - 2s (monotone in d^2 per row).
    // Runs while next tile's B/meta loads are in flight.
    #pragma unroll
    for (int cf = 0; cf < 4; ++cf) {
      const float sqc = mc[cf].x;
      const int tc = __float_as_int(mc[cf].y);
      #pragma unroll
      for (int rf = 0; rf < 2; ++rf)
        #pragma unroll
        for (int rg = 0; rg < 4; ++rg) {
          int idx = rf * 4 + rg;
          float v = fmaf(-2.f, acc[rf][cf][rg], sqc);
          bool pos = (t_r[idx] == tc);
          ap2[idx] = pos ? fmaxf(ap2[idx], v) : ap2[idx];
          an2[idx] = pos ? an2[idx] : fminf(an2[idx], v);
        }
    }
    #pragma unroll
    for (int cf = 0; cf < 4; ++cf) mc[cf] = mn[cf];
  }

  // reduce across the 16 lanes (same l4 group = same rows, different cols)
  #pragma unroll
  for (int i = 0; i < 8; ++i) {
    #pragma unroll
    for (int off = 1; off < 16; off <<= 1) {
      ap2[i] = fmaxf(ap2[i], __shfl_xor(ap2[i], off));
      an2[i] = fminf(an2[i], __shfl_xor(an2[i], off));
    }
  }
  if (l15 == 0) {
    #pragma unroll
    for (int rf = 0; rf < 2; ++rf)
      #pragma unroll
      for (int rg = 0; rg < 4; ++rg) {
        int row = rb + rf * 16 + l4 * 4 + rg;
        float sqr = meta[row].x;
        // d^2 = v + sq_r; clamp >=1e-12 commutes with max/min; non-negative
        // floats are int-monotone -> int atomics give exact fp max/min.
        float a2 = fmaxf(ap2[rf * 4 + rg] + sqr, 1e-12f);
        float n2 = fmaxf(an2[rf * 4 + rg] + sqr, 1e-12f);
        atomicMax(apb + row, __float_as_int(a2));
        atomicMin(anb + row, __float_as_int(n2));
      }
  }
}

// ---------------- Kernel C: loss = mean(relu(sqrt(ap2)-sqrt(an2)+margin)) --
__global__ __launch_bounds__(1024) void loss_kernel(
    const int4v* __restrict__ apb, const int4v* __restrict__ anb,
    float* __restrict__ out) {
  __shared__ float red[16];
  float s = 0.f;
  for (int i = threadIdx.x; i < N_ROWS / 4; i += 1024) {
    int4v a4 = apb[i], n4 = anb[i];
    #pragma unroll
    for (int j = 0; j < 4; ++j) {
      float ap = sqrtf(__int_as_float(a4[j]));
      float an = sqrtf(__int_as_float(n4[j]));   // +inf sentinel -> relu(-inf)=0
      float li = ap - an + MARGIN_F;
      s += li > 0.f ? li : 0.f;
    }
  }
  #pragma unroll
  for (int off = 32; off >= 1; off >>= 1) s += __shfl_xor(s, off);
  const int w = threadIdx.x >> 6, l = threadIdx.x & 63;
  if (l == 0) red[w] = s;
  __syncthreads();
  if (threadIdx.x < 16) {
    float v = red[threadIdx.x];
    #pragma unroll
    for (int off = 8; off >= 1; off >>= 1) v += __shfl_xor(v, off);
    if (threadIdx.x == 0) out[0] = v / (float)N_ROWS;
  }
}

extern "C" void kernel_launch(void* const* d_in, const int* in_sizes, int n_in,
                              void* d_out, int out_size, void* d_ws, size_t ws_size,
                              hipStream_t stream) {
  const float* x = (const float*)d_in[0];
  const int* tgt = (const int*)d_in[1];
  float* out = (float*)d_out;

  char* ws = (char*)d_ws;
  unsigned short* xbB = (unsigned short*)ws;                // 2 MB fragment-major bf16
  float2* meta = (float2*)(ws + 2097152);                   // 64 KB (sq, tgt)
  int* apb = (int*)(ws + 2097152 + 65536);                  // 32 KB ap^2 bits
  int* anb = (int*)(ws + 2097152 + 65536 + 32768);          // 32 KB an^2 bits

  prep_kernel<<<2048, 256, 0, stream>>>(x, tgt, xbB, meta, apb, anb);
  gram_mine_kernel<<<dim3(64, 32), 256, 0, stream>>>(xbB, meta, apb, anb);
  loss_kernel<<<1, 1024, 0, stream>>>((const int4v*)apb, (const int4v*)anb, out);
}